// Round 2
// baseline (478.395 us; speedup 1.0000x reference)
//
#include <hip/hip_runtime.h>

#define D 128

typedef __attribute__((ext_vector_type(8))) short short8;
typedef __attribute__((ext_vector_type(4))) float floatx4;

__device__ __forceinline__ short f32_bf16(float f) {
    unsigned u = __builtin_bit_cast(unsigned, f);
    u += 0x7fffu + ((u >> 16) & 1u);          // RNE
    return (short)(u >> 16);
}

// physical XCD id (hwreg 20 = HW_REG_XCC_ID, bits [3:0]) — wave-uniform
__device__ __forceinline__ int xcd_id() {
    return __builtin_amdgcn_s_getreg(20 | (3 << 11)) & 7;
}

// ---------------------------------------------------------------------------
// K2: reduce out-degree replicas -> norm_src (runs AFTER fill, which now
// produces the out-degree histogram as a side effect of its edge scan).
// ---------------------------------------------------------------------------
__global__ __launch_bounds__(256) void k_norm_s(const int* __restrict__ ds_rep,
                                                float* __restrict__ norm_src,
                                                int N) {
    int i = blockIdx.x * 256 + threadIdx.x;
    if (i < N) {
        int s = 0;
        #pragma unroll
        for (int r = 0; r < 8; ++r) s += ds_rep[r * N + i];
        norm_src[i] = rsqrtf((float)max(s, 1));
    }
}

// ---------------------------------------------------------------------------
// K3: x -> bf16 copy (halves k_agg gather traffic)
// ---------------------------------------------------------------------------
__global__ __launch_bounds__(256) void k_cvt(const float* __restrict__ x,
                                             unsigned short* __restrict__ xb,
                                             int n8) {
    int i = blockIdx.x * 256 + threadIdx.x;
    if (i < n8) {
        float4 a = ((const float4*)x)[2 * i];
        float4 b = ((const float4*)x)[2 * i + 1];
        short8 v;
        v[0] = f32_bf16(a.x); v[1] = f32_bf16(a.y);
        v[2] = f32_bf16(a.z); v[3] = f32_bf16(a.w);
        v[4] = f32_bf16(b.x); v[5] = f32_bf16(b.y);
        v[6] = f32_bf16(b.z); v[7] = f32_bf16(b.w);
        *(short8*)(xb + i * 8) = v;
    }
}

// ---------------------------------------------------------------------------
// K4: single-owner windowed fill (counting scatter, packed rows).
// dst-space is split into 8 windows. A window is processed EXCLUSIVELY by one
// XCD: blocks claim windows via device-scope CAS (native window first), then
// drain per-window chunk tickets with workgroup-scope atomics (single-XCD ->
// L2-local, same pattern the replica scheme verified). Packed rows: slot =
// atomicAdd(cnt[d]) -> csr[d*PITCH+slot]; a node's ~16 ids land in 1-2 64B
// lines owned by ONE L2 instead of 8 replica lines -> ~5x less writeback.
// Out-degree histogram (replica per processing XCD) fused into the same scan.
// Cost: each window's owner scans all E edges (8x reads, MALL-served).
// Placement-robust: every block CASes every window, so all windows get
// drained even under pathological block->XCD placement.
// ---------------------------------------------------------------------------
#define CH_I4 256   // int4s per chunk = 1024 edges

template<int PITCH>
__device__ __forceinline__ void fill_edge(int d, int s, int lo, unsigned span,
                                          int r, int* __restrict__ out_rep,
                                          int* __restrict__ cnt,
                                          int* __restrict__ csr, int N) {
    if ((unsigned)(d - lo) < span) {
        __hip_atomic_fetch_add(&out_rep[r * N + s], 1,
                               __ATOMIC_RELAXED, __HIP_MEMORY_SCOPE_WORKGROUP);
        int slot = __hip_atomic_fetch_add(&cnt[d], 1,
                                          __ATOMIC_RELAXED,
                                          __HIP_MEMORY_SCOPE_WORKGROUP);
        if (slot < PITCH) csr[d * PITCH + slot] = s;
    }
}

template<int PITCH>
__global__ __launch_bounds__(256) void k_fill(const int* __restrict__ src,
                                              const int* __restrict__ dst,
                                              int* __restrict__ out_rep,
                                              int* __restrict__ cnt,
                                              int* __restrict__ csr,
                                              int* __restrict__ tick,
                                              int* __restrict__ owner,
                                              int E, int N, int NC) {
    const int r = xcd_id();
    const int nv4 = E >> 2;
    const int4* __restrict__ src4 = (const int4*)src;
    const int4* __restrict__ dst4 = (const int4*)dst;
    __shared__ int s_val;

    for (int step = 0; step < 8; ++step) {
        const int w = (r + step) & 7;
        if (threadIdx.x == 0) {
            int exp = -1;
            __hip_atomic_compare_exchange_strong(&owner[w], &exp, r,
                                                 __ATOMIC_RELAXED, __ATOMIC_RELAXED,
                                                 __HIP_MEMORY_SCOPE_AGENT);
            s_val = (exp == -1) ? r : exp;   // exp holds prev owner on failure
        }
        __syncthreads();
        const int own = s_val;
        __syncthreads();
        if (own != r) continue;              // another XCD owns this window

        const int lo = (int)((long long)N * w / 8);
        const int hi = (int)((long long)N * (w + 1) / 8);
        const unsigned span = (unsigned)(hi - lo);

        for (;;) {
            if (threadIdx.x == 0)
                s_val = __hip_atomic_fetch_add(&tick[w], 1,
                                               __ATOMIC_RELAXED,
                                               __HIP_MEMORY_SCOPE_WORKGROUP);
            __syncthreads();
            const int c = s_val;
            __syncthreads();
            if (c >= NC) break;

            int v = c * CH_I4 + threadIdx.x;
            if (v < nv4) {
                int4 d4 = dst4[v];
                int4 s4 = src4[v];
                fill_edge<PITCH>(d4.x, s4.x, lo, span, r, out_rep, cnt, csr, N);
                fill_edge<PITCH>(d4.y, s4.y, lo, span, r, out_rep, cnt, csr, N);
                fill_edge<PITCH>(d4.z, s4.z, lo, span, r, out_rep, cnt, csr, N);
                fill_edge<PITCH>(d4.w, s4.w, lo, span, r, out_rep, cnt, csr, N);
            }
            if (c == NC - 1) {               // scalar tail, E & 3 edges
                int e = (nv4 << 2) + threadIdx.x;
                if (e < E)
                    fill_edge<PITCH>(dst[e], src[e], lo, span, r, out_rep, cnt, csr, N);
            }
        }
    }
}

// ---------------------------------------------------------------------------
// K5: per-node aggregation. Rows are now DENSE (packed fill): ids are
// csr[n*PITCH .. n*PITCH+deg), deg_true = cnt[n]. One wave per node; stage
// ids to LDS (wave-uniform broadcast reads), unroll-4 gather loop.
// ---------------------------------------------------------------------------
template<int PITCH>
__global__ __launch_bounds__(256) void k_agg(const int* __restrict__ csr,
                                             const int* __restrict__ cnt,
                                             const float* __restrict__ norm_src,
                                             const unsigned int* __restrict__ xb,
                                             const float* __restrict__ x,
                                             float* __restrict__ agg, int N) {
    __shared__ int ids_s[4][PITCH];
    const int w = threadIdx.x >> 6;
    const int lane = threadIdx.x & 63;
    int n = blockIdx.x * 4 + w;
    if (n >= N) n = N - 1;              // duplicate work; keeps barriers uniform

    const int deg_true = cnt[n];
    const int deg = min(deg_true, PITCH);

    #pragma unroll
    for (int j = 0; j < PITCH / 64; ++j) {
        int idx = lane + j * 64;
        if (idx < deg) ids_s[w][idx] = csr[n * PITCH + idx];
    }
    __syncthreads();

    const int* ids = ids_s[w];
    float ax = 0.f, ay = 0.f;
    if (xb) {
        int i = 0;
        for (; i + 4 <= deg; i += 4) {
            int s0 = ids[i];
            int s1 = ids[i + 1];
            int s2 = ids[i + 2];
            int s3 = ids[i + 3];
            float a0 = norm_src[s0];
            float a1 = norm_src[s1];
            float a2 = norm_src[s2];
            float a3 = norm_src[s3];
            unsigned u0 = xb[s0 * 64 + lane];
            unsigned u1 = xb[s1 * 64 + lane];
            unsigned u2 = xb[s2 * 64 + lane];
            unsigned u3 = xb[s3 * 64 + lane];
            ax = fmaf(__builtin_bit_cast(float, u0 << 16), a0, ax);
            ay = fmaf(__builtin_bit_cast(float, u0 & 0xffff0000u), a0, ay);
            ax = fmaf(__builtin_bit_cast(float, u1 << 16), a1, ax);
            ay = fmaf(__builtin_bit_cast(float, u1 & 0xffff0000u), a1, ay);
            ax = fmaf(__builtin_bit_cast(float, u2 << 16), a2, ax);
            ay = fmaf(__builtin_bit_cast(float, u2 & 0xffff0000u), a2, ay);
            ax = fmaf(__builtin_bit_cast(float, u3 << 16), a3, ax);
            ay = fmaf(__builtin_bit_cast(float, u3 & 0xffff0000u), a3, ay);
        }
        for (; i < deg; ++i) {
            int s0 = ids[i];
            float a0 = norm_src[s0];
            unsigned u0 = xb[s0 * 64 + lane];
            ax = fmaf(__builtin_bit_cast(float, u0 << 16), a0, ax);
            ay = fmaf(__builtin_bit_cast(float, u0 & 0xffff0000u), a0, ay);
        }
    } else {
        const float2* __restrict__ x2 = (const float2*)x;
        int i = 0;
        for (; i + 4 <= deg; i += 4) {
            int s0 = ids[i];
            int s1 = ids[i + 1];
            int s2 = ids[i + 2];
            int s3 = ids[i + 3];
            float a0 = norm_src[s0];
            float a1 = norm_src[s1];
            float a2 = norm_src[s2];
            float a3 = norm_src[s3];
            float2 v0 = x2[s0 * 64 + lane];
            float2 v1 = x2[s1 * 64 + lane];
            float2 v2 = x2[s2 * 64 + lane];
            float2 v3 = x2[s3 * 64 + lane];
            ax = fmaf(v0.x, a0, ax); ay = fmaf(v0.y, a0, ay);
            ax = fmaf(v1.x, a1, ax); ay = fmaf(v1.y, a1, ay);
            ax = fmaf(v2.x, a2, ax); ay = fmaf(v2.y, a2, ay);
            ax = fmaf(v3.x, a3, ax); ay = fmaf(v3.y, a3, ay);
        }
        for (; i < deg; ++i) {
            int s0 = ids[i];
            float a0 = norm_src[s0];
            float2 v0 = x2[s0 * 64 + lane];
            ax = fmaf(v0.x, a0, ax); ay = fmaf(v0.y, a0, ay);
        }
    }
    float nd = rsqrtf((float)max(deg_true, 1));
    ((float2*)agg)[n * 64 + lane] = make_float2(ax * nd, ay * nd);
}

// ---------------------------------------------------------------------------
// K6: MFMA bf16 GEMM + NodeNorm + relu + residual (unchanged).
// ---------------------------------------------------------------------------
#define WT_STRIDE 136
#define H_STRIDE  132

__global__ __launch_bounds__(256, 2) void k_gemm_norm(
    const float* __restrict__ agg,
    const float* __restrict__ x,
    const float* __restrict__ W,
    const float* __restrict__ bias,
    float* __restrict__ out, int N)
{
    __shared__ char raw[D * WT_STRIDE * 2];           // 34816 B >= 64*132*4
    short* Wt = (short*)raw;                          // Wt[c][k], bf16
    float* h  = (float*)raw;                          // h[64][H_STRIDE], after

    const int t = threadIdx.x;
    const int lane = t & 63;
    const int w = t >> 6;
    const int row0 = blockIdx.x * 64;

    #pragma unroll 4
    for (int i = 0; i < 64; ++i) {
        int idx = t + i * 256;
        int k = idx >> 7, c = idx & 127;
        Wt[c * WT_STRIDE + k] = f32_bf16(W[idx]);
    }
    __syncthreads();

    const int col16 = lane & 15;
    const int quad  = lane >> 4;
    int arow = row0 + w * 16 + col16;
    if (arow >= N) arow = N - 1;
    const float* aptr = agg + (long long)arow * D + quad * 8;

    floatx4 acc[8];
    #pragma unroll
    for (int c = 0; c < 8; ++c) {
        float b = bias[c * 16 + col16];
        acc[c] = (floatx4){b, b, b, b};
    }

    #pragma unroll
    for (int kc = 0; kc < 4; ++kc) {
        float4 a0 = *(const float4*)(aptr + kc * 32);
        float4 a1 = *(const float4*)(aptr + kc * 32 + 4);
        short8 af;
        af[0] = f32_bf16(a0.x); af[1] = f32_bf16(a0.y);
        af[2] = f32_bf16(a0.z); af[3] = f32_bf16(a0.w);
        af[4] = f32_bf16(a1.x); af[5] = f32_bf16(a1.y);
        af[6] = f32_bf16(a1.z); af[7] = f32_bf16(a1.w);
        const short* wbase = Wt + kc * 32 + quad * 8;
        #pragma unroll
        for (int c = 0; c < 8; ++c) {
            short8 bf = *(const short8*)(wbase + (c * 16 + col16) * WT_STRIDE);
            acc[c] = __builtin_amdgcn_mfma_f32_16x16x32_bf16(af, bf, acc[c], 0, 0, 0);
        }
    }
    __syncthreads();

    #pragma unroll
    for (int c = 0; c < 8; ++c) {
        #pragma unroll
        for (int i = 0; i < 4; ++i) {
            h[(w * 16 + quad * 4 + i) * H_STRIDE + c * 16 + col16] = acc[c][i];
        }
    }
    __syncthreads();

    const int row = t >> 2;
    const int part = t & 3;
    const float* hp = h + row * H_STRIDE + part * 32;
    float4 hv[8];
    float s = 0.f, ss = 0.f;
    #pragma unroll
    for (int i = 0; i < 8; ++i) {
        float4 v = *(const float4*)(hp + i * 4);
        hv[i] = v;
        s  += v.x + v.y + v.z + v.w;
        ss += v.x * v.x + v.y * v.y + v.z * v.z + v.w * v.w;
    }
    s += __shfl_xor(s, 1); ss += __shfl_xor(ss, 1);
    s += __shfl_xor(s, 2); ss += __shfl_xor(ss, 2);
    const float mean = s * (1.0f / 128.0f);
    const float var = ss * (1.0f / 128.0f) - mean * mean;
    const float inv = rsqrtf(var + 1e-5f);
    const int grow = row0 + row;
    if (grow < N) {
        const float* xp = x + (long long)grow * D + part * 32;
        float* op = out + (long long)grow * D + part * 32;
        #pragma unroll
        for (int i = 0; i < 8; ++i) {
            float4 v = hv[i];
            float4 xr = *(const float4*)(xp + i * 4);
            float4 o;
            o.x = fmaxf((v.x - mean) * inv, 0.f) + xr.x;
            o.y = fmaxf((v.y - mean) * inv, 0.f) + xr.y;
            o.z = fmaxf((v.z - mean) * inv, 0.f) + xr.z;
            o.w = fmaxf((v.w - mean) * inv, 0.f) + xr.w;
            *(float4*)(op + i * 4) = o;
        }
    }
}

// ---------------------------------------------------------------------------
extern "C" void kernel_launch(void* const* d_in, const int* in_sizes, int n_in,
                              void* d_out, int out_size, void* d_ws, size_t ws_size,
                              hipStream_t stream) {
    const float* x    = (const float*)d_in[0];
    const float* W    = (const float*)d_in[1];
    const float* bias = (const float*)d_in[2];
    const int*   src  = (const int*)d_in[3];
    const int*   dst  = (const int*)d_in[4];
    const int N = in_sizes[0] / D;
    const int E = in_sizes[3];
    float* out = (float*)d_out;

    const size_t AL = 255;
    size_t ctrl_b    = 256;                               // tick[8] + owner[8]
    size_t outrep_b  = (((size_t)8 * N * 4) + AL) & ~AL;
    size_t cnt_b     = (((size_t)N * 4) + AL) & ~AL;
    size_t nsrc_b    = (((size_t)N * 4) + AL) & ~AL;
    size_t csr128_b  = (((size_t)N * 128 * 4) + AL) & ~AL;
    size_t csr64_b   = (((size_t)N * 64 * 4) + AL) & ~AL;
    size_t xb_b      = (((size_t)N * D * 2) + AL) & ~AL;

    size_t fixed = ctrl_b + outrep_b + cnt_b + nsrc_b;
    bool p128, use_bf;
    if (ws_size >= fixed + csr128_b + xb_b)      { p128 = true;  use_bf = true;  }
    else if (ws_size >= fixed + csr64_b + xb_b)  { p128 = false; use_bf = true;  }
    else                                         { p128 = false; use_bf = false; }

    char* p = (char*)d_ws;
    int*   tick   = (int*)p;
    int*   owner  = (int*)(p + 64);          p += ctrl_b;
    int*   outrep = (int*)p;                 p += outrep_b;
    int*   cnt    = (int*)p;                 p += cnt_b;
    float* nsrc   = (float*)p;               p += nsrc_b;
    int*   csr    = (int*)p;                 p += p128 ? csr128_b : csr64_b;
    unsigned short* xb = (unsigned short*)p;

    float* agg = out;      // alias output as aggregation buffer

    // out_rep and cnt are contiguous: one memset covers both
    hipMemsetAsync(outrep, 0, outrep_b + cnt_b, stream);
    hipMemsetAsync(tick, 0, 64, stream);
    hipMemsetAsync(owner, 0xFF, 64, stream);

    const int nv4 = E >> 2;
    int NC = (nv4 + CH_I4 - 1) / CH_I4;
    if (NC < 1) NC = 1;
    const int NB = (N + 255) / 256;
    const int FB = 1024;   // 128 blocks/XCD under round-robin placement

    if (use_bf) {
        int n8 = N * D / 8;
        k_cvt<<<(n8 + 255) / 256, 256, 0, stream>>>(x, xb, n8);
    }
    const unsigned int* xbp = use_bf ? (const unsigned int*)xb : nullptr;

    if (p128) {
        k_fill<128><<<FB, 256, 0, stream>>>(src, dst, outrep, cnt, csr,
                                            tick, owner, E, N, NC);
        k_norm_s<<<NB, 256, 0, stream>>>(outrep, nsrc, N);
        k_agg<128><<<(N + 3) / 4, 256, 0, stream>>>(csr, cnt, nsrc, xbp, x, agg, N);
    } else {
        k_fill<64><<<FB, 256, 0, stream>>>(src, dst, outrep, cnt, csr,
                                           tick, owner, E, N, NC);
        k_norm_s<<<NB, 256, 0, stream>>>(outrep, nsrc, N);
        k_agg<64><<<(N + 3) / 4, 256, 0, stream>>>(csr, cnt, nsrc, xbp, x, agg, N);
    }
    k_gemm_norm<<<(N + 63) / 64, 256, 0, stream>>>(agg, x, W, bias, out, N);
}

// Round 3
// 370.174 us; speedup vs baseline: 1.2924x; 1.2924x over previous
//
#include <hip/hip_runtime.h>

#define D 128
#define FILL_PASSES 8

typedef __attribute__((ext_vector_type(8))) short short8;
typedef __attribute__((ext_vector_type(4))) float floatx4;

__device__ __forceinline__ short f32_bf16(float f) {
    unsigned u = __builtin_bit_cast(unsigned, f);
    u += 0x7fffu + ((u >> 16) & 1u);          // RNE
    return (short)(u >> 16);
}

// physical XCD id (hwreg 20 = HW_REG_XCC_ID, bits [3:0]) — wave-uniform
__device__ __forceinline__ int xcd_id() {
    return __builtin_amdgcn_s_getreg(20 | (3 << 11)) & 7;
}

// ---------------------------------------------------------------------------
// K1 (fallback tiers only): out-degree histogram, XCD replicas, int4 loads.
// ---------------------------------------------------------------------------
__global__ __launch_bounds__(256) void k_deg_s(const int* __restrict__ src,
                                               int* __restrict__ ds_rep,
                                               int E, int N) {
    const int r = xcd_id();
    const int t = blockIdx.x * 256 + threadIdx.x;
    const int nv = E >> 2;
    if (t < nv) {
        int4 s = ((const int4*)src)[t];
        __hip_atomic_fetch_add(&ds_rep[r * N + s.x], 1,
                               __ATOMIC_RELAXED, __HIP_MEMORY_SCOPE_WORKGROUP);
        __hip_atomic_fetch_add(&ds_rep[r * N + s.y], 1,
                               __ATOMIC_RELAXED, __HIP_MEMORY_SCOPE_WORKGROUP);
        __hip_atomic_fetch_add(&ds_rep[r * N + s.z], 1,
                               __ATOMIC_RELAXED, __HIP_MEMORY_SCOPE_WORKGROUP);
        __hip_atomic_fetch_add(&ds_rep[r * N + s.w], 1,
                               __ATOMIC_RELAXED, __HIP_MEMORY_SCOPE_WORKGROUP);
    }
    int e = (nv << 2) + t;
    if (e < E) {
        __hip_atomic_fetch_add(&ds_rep[r * N + src[e]], 1,
                               __ATOMIC_RELAXED, __HIP_MEMORY_SCOPE_WORKGROUP);
    }
}

// ---------------------------------------------------------------------------
// K2: reduce replicas -> norm_src
// ---------------------------------------------------------------------------
__global__ __launch_bounds__(256) void k_norm_s(const int* __restrict__ ds_rep,
                                                float* __restrict__ norm_src,
                                                int N) {
    int i = blockIdx.x * 256 + threadIdx.x;
    if (i < N) {
        int s = 0;
        #pragma unroll
        for (int r = 0; r < 8; ++r) s += ds_rep[r * N + i];
        norm_src[i] = rsqrtf((float)max(s, 1));
    }
}

// ---------------------------------------------------------------------------
// K3: x -> bf16 copy (halves k_agg gather traffic)
// ---------------------------------------------------------------------------
__global__ __launch_bounds__(256) void k_cvt(const float* __restrict__ x,
                                             unsigned short* __restrict__ xb,
                                             int n8) {
    int i = blockIdx.x * 256 + threadIdx.x;
    if (i < n8) {
        float4 a = ((const float4*)x)[2 * i];
        float4 b = ((const float4*)x)[2 * i + 1];
        short8 v;
        v[0] = f32_bf16(a.x); v[1] = f32_bf16(a.y);
        v[2] = f32_bf16(a.z); v[3] = f32_bf16(a.w);
        v[4] = f32_bf16(b.x); v[5] = f32_bf16(b.y);
        v[6] = f32_bf16(b.z); v[7] = f32_bf16(b.w);
        *(short8*)(xb + i * 8) = v;
    }
}

// ---------------------------------------------------------------------------
// K4: dst-tiled ELL fill — ROUND-0 STRUCTURE (replica ELL, PASSES=8: the
// per-pass store window of ~800KB/XCD is what keeps writeback at 12x; both
// larger-window variants measured worse). Changes vs round 0:
//  * int4 loads of dst AND src: 2 independent 16B loads + 4 independent
//    atomic/store chains per iter (round-0 scalar version had VGPR=8, zero ILP).
//  * pass 0 optionally fuses the out-degree histogram (deletes k_deg_s).
// R=8: XCD-local workgroup-scope slot allocators; R=1 fallback: agent-scope.
// ---------------------------------------------------------------------------
template<int R, int SUBCAP>
__device__ __forceinline__ void fill_one(int d, int s, int lo, unsigned span,
                                         int r, int* __restrict__ cnt,
                                         int* __restrict__ csr, int N) {
    if ((unsigned)(d - lo) < span) {
        int slot;
        if (R == 8) {
            slot = __hip_atomic_fetch_add(&cnt[r * N + d], 1,
                                          __ATOMIC_RELAXED,
                                          __HIP_MEMORY_SCOPE_WORKGROUP);
        } else {
            slot = atomicAdd(&cnt[d], 1);
        }
        if (slot < SUBCAP) csr[d * (R * SUBCAP) + r * SUBCAP + slot] = s;
    }
}

__device__ __forceinline__ void deg_one(int s, int r, int* __restrict__ out_rep,
                                        int N) {
    __hip_atomic_fetch_add(&out_rep[r * N + s], 1,
                           __ATOMIC_RELAXED, __HIP_MEMORY_SCOPE_WORKGROUP);
}

template<int R, int SUBCAP, bool FUSE_DEG>
__global__ __launch_bounds__(256) void k_fill_t(const int* __restrict__ src,
                                                const int* __restrict__ dst,
                                                int* __restrict__ out_rep,
                                                int* __restrict__ cnt,
                                                int* __restrict__ csr,
                                                int E, int N) {
    const int r = (R == 8) ? xcd_id() : 0;
    const int rd = xcd_id();               // deg replicas always per-XCD
    const int stride = gridDim.x * 256;
    const int nv4 = E >> 2;
    const int4* __restrict__ src4 = (const int4*)src;
    const int4* __restrict__ dst4 = (const int4*)dst;
    for (int p = 0; p < FILL_PASSES; ++p) {
        const int lo = (int)((long long)N * p / FILL_PASSES);
        const int hi = (int)((long long)N * (p + 1) / FILL_PASSES);
        const unsigned span = (unsigned)(hi - lo);
        for (int v = blockIdx.x * 256 + threadIdx.x; v < nv4; v += stride) {
            int4 d4 = dst4[v];
            int4 s4 = src4[v];
            if (FUSE_DEG && p == 0) {
                deg_one(s4.x, rd, out_rep, N);
                deg_one(s4.y, rd, out_rep, N);
                deg_one(s4.z, rd, out_rep, N);
                deg_one(s4.w, rd, out_rep, N);
            }
            fill_one<R, SUBCAP>(d4.x, s4.x, lo, span, r, cnt, csr, N);
            fill_one<R, SUBCAP>(d4.y, s4.y, lo, span, r, cnt, csr, N);
            fill_one<R, SUBCAP>(d4.z, s4.z, lo, span, r, cnt, csr, N);
            fill_one<R, SUBCAP>(d4.w, s4.w, lo, span, r, cnt, csr, N);
        }
        // scalar tail: E & 3 edges
        for (int e = (nv4 << 2) + blockIdx.x * 256 + threadIdx.x; e < E;
             e += stride) {
            int d = dst[e];
            int s = src[e];
            if (FUSE_DEG && p == 0) deg_one(s, rd, out_rep, N);
            fill_one<R, SUBCAP>(d, s, lo, span, r, cnt, csr, N);
        }
    }
}

// ---------------------------------------------------------------------------
// K5: per-node aggregation. One wave per node. Stage the node's R*SUBCAP ELL
// slots into LDS (coalesced), compact valid ids using the per-replica counts,
// then run a tight unroll-4 gather loop over the dense id list (wave-uniform
// ds_read broadcast) -> 8 gathers in flight.
// ---------------------------------------------------------------------------
template<int R, int SUBCAP>
__global__ __launch_bounds__(256) void k_agg(const int* __restrict__ csr,
                                             const int* __restrict__ cnt,
                                             const float* __restrict__ norm_src,
                                             const unsigned int* __restrict__ xb,
                                             const float* __restrict__ x,
                                             float* __restrict__ agg, int N) {
    __shared__ int ids_s[4][R * SUBCAP];
    const int w = threadIdx.x >> 6;
    const int lane = threadIdx.x & 63;
    int n = blockIdx.x * 4 + w;
    if (n >= N) n = N - 1;              // duplicate work; keeps barriers uniform

    int cr[R], off[R + 1];
    int deg_true = 0;
    off[0] = 0;
    #pragma unroll
    for (int r = 0; r < R; ++r) {
        int c = cnt[r * N + n];
        deg_true += c;
        cr[r] = min(c, SUBCAP);
        off[r + 1] = off[r] + cr[r];
    }
    const int deg = off[R];

    // stage + compact: slot idx -> (replica idx/SUBCAP, pos idx%SUBCAP)
    #pragma unroll
    for (int j = 0; j < (R * SUBCAP + 63) / 64; ++j) {
        int idx = lane + j * 64;
        if (idx < R * SUBCAP) {
            int rr = idx / SUBCAP;
            int ss = idx % SUBCAP;
            if (ss < cr[rr]) ids_s[w][off[rr] + ss] = csr[n * (R * SUBCAP) + idx];
        }
    }
    __syncthreads();

    const int* ids = ids_s[w];
    float ax = 0.f, ay = 0.f;
    if (xb) {
        int i = 0;
        for (; i + 4 <= deg; i += 4) {
            int s0 = ids[i];
            int s1 = ids[i + 1];
            int s2 = ids[i + 2];
            int s3 = ids[i + 3];
            float a0 = norm_src[s0];
            float a1 = norm_src[s1];
            float a2 = norm_src[s2];
            float a3 = norm_src[s3];
            unsigned u0 = xb[s0 * 64 + lane];
            unsigned u1 = xb[s1 * 64 + lane];
            unsigned u2 = xb[s2 * 64 + lane];
            unsigned u3 = xb[s3 * 64 + lane];
            ax = fmaf(__builtin_bit_cast(float, u0 << 16), a0, ax);
            ay = fmaf(__builtin_bit_cast(float, u0 & 0xffff0000u), a0, ay);
            ax = fmaf(__builtin_bit_cast(float, u1 << 16), a1, ax);
            ay = fmaf(__builtin_bit_cast(float, u1 & 0xffff0000u), a1, ay);
            ax = fmaf(__builtin_bit_cast(float, u2 << 16), a2, ax);
            ay = fmaf(__builtin_bit_cast(float, u2 & 0xffff0000u), a2, ay);
            ax = fmaf(__builtin_bit_cast(float, u3 << 16), a3, ax);
            ay = fmaf(__builtin_bit_cast(float, u3 & 0xffff0000u), a3, ay);
        }
        for (; i < deg; ++i) {
            int s0 = ids[i];
            float a0 = norm_src[s0];
            unsigned u0 = xb[s0 * 64 + lane];
            ax = fmaf(__builtin_bit_cast(float, u0 << 16), a0, ax);
            ay = fmaf(__builtin_bit_cast(float, u0 & 0xffff0000u), a0, ay);
        }
    } else {
        const float2* __restrict__ x2 = (const float2*)x;
        int i = 0;
        for (; i + 4 <= deg; i += 4) {
            int s0 = ids[i];
            int s1 = ids[i + 1];
            int s2 = ids[i + 2];
            int s3 = ids[i + 3];
            float a0 = norm_src[s0];
            float a1 = norm_src[s1];
            float a2 = norm_src[s2];
            float a3 = norm_src[s3];
            float2 v0 = x2[s0 * 64 + lane];
            float2 v1 = x2[s1 * 64 + lane];
            float2 v2 = x2[s2 * 64 + lane];
            float2 v3 = x2[s3 * 64 + lane];
            ax = fmaf(v0.x, a0, ax); ay = fmaf(v0.y, a0, ay);
            ax = fmaf(v1.x, a1, ax); ay = fmaf(v1.y, a1, ay);
            ax = fmaf(v2.x, a2, ax); ay = fmaf(v2.y, a2, ay);
            ax = fmaf(v3.x, a3, ax); ay = fmaf(v3.y, a3, ay);
        }
        for (; i < deg; ++i) {
            int s0 = ids[i];
            float a0 = norm_src[s0];
            float2 v0 = x2[s0 * 64 + lane];
            ax = fmaf(v0.x, a0, ax); ay = fmaf(v0.y, a0, ay);
        }
    }
    float nd = rsqrtf((float)max(deg_true, 1));
    ((float2*)agg)[n * 64 + lane] = make_float2(ax * nd, ay * nd);
}

// ---------------------------------------------------------------------------
// K6: MFMA bf16 GEMM + NodeNorm + relu + residual (unchanged).
// ---------------------------------------------------------------------------
#define WT_STRIDE 136
#define H_STRIDE  132

__global__ __launch_bounds__(256, 2) void k_gemm_norm(
    const float* __restrict__ agg,
    const float* __restrict__ x,
    const float* __restrict__ W,
    const float* __restrict__ bias,
    float* __restrict__ out, int N)
{
    __shared__ char raw[D * WT_STRIDE * 2];           // 34816 B >= 64*132*4
    short* Wt = (short*)raw;                          // Wt[c][k], bf16
    float* h  = (float*)raw;                          // h[64][H_STRIDE], after

    const int t = threadIdx.x;
    const int lane = t & 63;
    const int w = t >> 6;
    const int row0 = blockIdx.x * 64;

    #pragma unroll 4
    for (int i = 0; i < 64; ++i) {
        int idx = t + i * 256;
        int k = idx >> 7, c = idx & 127;
        Wt[c * WT_STRIDE + k] = f32_bf16(W[idx]);
    }
    __syncthreads();

    const int col16 = lane & 15;
    const int quad  = lane >> 4;
    int arow = row0 + w * 16 + col16;
    if (arow >= N) arow = N - 1;
    const float* aptr = agg + (long long)arow * D + quad * 8;

    floatx4 acc[8];
    #pragma unroll
    for (int c = 0; c < 8; ++c) {
        float b = bias[c * 16 + col16];
        acc[c] = (floatx4){b, b, b, b};
    }

    #pragma unroll
    for (int kc = 0; kc < 4; ++kc) {
        float4 a0 = *(const float4*)(aptr + kc * 32);
        float4 a1 = *(const float4*)(aptr + kc * 32 + 4);
        short8 af;
        af[0] = f32_bf16(a0.x); af[1] = f32_bf16(a0.y);
        af[2] = f32_bf16(a0.z); af[3] = f32_bf16(a0.w);
        af[4] = f32_bf16(a1.x); af[5] = f32_bf16(a1.y);
        af[6] = f32_bf16(a1.z); af[7] = f32_bf16(a1.w);
        const short* wbase = Wt + kc * 32 + quad * 8;
        #pragma unroll
        for (int c = 0; c < 8; ++c) {
            short8 bf = *(const short8*)(wbase + (c * 16 + col16) * WT_STRIDE);
            acc[c] = __builtin_amdgcn_mfma_f32_16x16x32_bf16(af, bf, acc[c], 0, 0, 0);
        }
    }
    __syncthreads();

    #pragma unroll
    for (int c = 0; c < 8; ++c) {
        #pragma unroll
        for (int i = 0; i < 4; ++i) {
            h[(w * 16 + quad * 4 + i) * H_STRIDE + c * 16 + col16] = acc[c][i];
        }
    }
    __syncthreads();

    const int row = t >> 2;
    const int part = t & 3;
    const float* hp = h + row * H_STRIDE + part * 32;
    float4 hv[8];
    float s = 0.f, ss = 0.f;
    #pragma unroll
    for (int i = 0; i < 8; ++i) {
        float4 v = *(const float4*)(hp + i * 4);
        hv[i] = v;
        s  += v.x + v.y + v.z + v.w;
        ss += v.x * v.x + v.y * v.y + v.z * v.z + v.w * v.w;
    }
    s += __shfl_xor(s, 1); ss += __shfl_xor(ss, 1);
    s += __shfl_xor(s, 2); ss += __shfl_xor(ss, 2);
    const float mean = s * (1.0f / 128.0f);
    const float var = ss * (1.0f / 128.0f) - mean * mean;
    const float inv = rsqrtf(var + 1e-5f);
    const int grow = row0 + row;
    if (grow < N) {
        const float* xp = x + (long long)grow * D + part * 32;
        float* op = out + (long long)grow * D + part * 32;
        #pragma unroll
        for (int i = 0; i < 8; ++i) {
            float4 v = hv[i];
            float4 xr = *(const float4*)(xp + i * 4);
            float4 o;
            o.x = fmaxf((v.x - mean) * inv, 0.f) + xr.x;
            o.y = fmaxf((v.y - mean) * inv, 0.f) + xr.y;
            o.z = fmaxf((v.z - mean) * inv, 0.f) + xr.z;
            o.w = fmaxf((v.w - mean) * inv, 0.f) + xr.w;
            *(float4*)(op + i * 4) = o;
        }
    }
}

// ---------------------------------------------------------------------------
extern "C" void kernel_launch(void* const* d_in, const int* in_sizes, int n_in,
                              void* d_out, int out_size, void* d_ws, size_t ws_size,
                              hipStream_t stream) {
    const float* x    = (const float*)d_in[0];
    const float* W    = (const float*)d_in[1];
    const float* bias = (const float*)d_in[2];
    const int*   src  = (const int*)d_in[3];
    const int*   dst  = (const int*)d_in[4];
    const int N = in_sizes[0] / D;
    const int E = in_sizes[3];
    float* out = (float*)d_out;

    const size_t AL = 255;
    size_t cnt_rep_b = (((size_t)8 * N * 4) + AL) & ~AL;
    size_t cnt_one_b = (((size_t)N * 4) + AL) & ~AL;
    size_t outrep_b  = (((size_t)8 * N * 4) + AL) & ~AL;
    size_t nsrc_b    = (((size_t)N * 4) + AL) & ~AL;
    size_t csr128_b  = (((size_t)N * 128 * 4) + AL) & ~AL;
    size_t csr64_b   = (((size_t)N * 64 * 4) + AL) & ~AL;
    size_t xb_b      = (((size_t)N * D * 2) + AL) & ~AL;

    // Tiers: A fused+rep+bf | A2 round-0 exact (rep+bf, separate deg)
    //        B fused+rep    | C rep-only      | D minimal
    bool use_rep, use_bf, fuse;
    if (ws_size >= cnt_rep_b + outrep_b + nsrc_b + csr128_b + xb_b) {
        use_rep = true;  use_bf = true;  fuse = true;
    } else if (ws_size >= cnt_rep_b + nsrc_b + csr128_b + xb_b) {
        use_rep = true;  use_bf = true;  fuse = false;
    } else if (ws_size >= cnt_rep_b + outrep_b + nsrc_b + csr128_b) {
        use_rep = true;  use_bf = false; fuse = true;
    } else if (ws_size >= cnt_one_b + nsrc_b + csr64_b + xb_b) {
        use_rep = false; use_bf = true;  fuse = false;
    } else {
        use_rep = false; use_bf = false; fuse = false;
    }

    char* p = (char*)d_ws;
    size_t cnt_b = use_rep ? cnt_rep_b : cnt_one_b;
    size_t csr_b = use_rep ? csr128_b  : csr64_b;
    int*   cnt  = (int*)p;                    p += cnt_b;
    int*   outrep = nullptr;
    if (fuse) { outrep = (int*)p;             p += outrep_b; }
    float* nsrc = (float*)p;                  p += nsrc_b;
    int*   csr  = (int*)p;                    p += csr_b;
    unsigned short* xb = (unsigned short*)p;
    int*   ds_rep = fuse ? outrep : csr;  // non-fused: 8N ints alias csr
                                          // (dead before fill)

    float* agg = out;      // alias output as aggregation buffer

    if (fuse) {
        hipMemsetAsync(cnt, 0, cnt_b + outrep_b, stream);  // contiguous
    } else {
        hipMemsetAsync(cnt, 0, cnt_b, stream);
        hipMemsetAsync(ds_rep, 0, (size_t)8 * N * sizeof(int), stream);
    }

    const int nv4 = E >> 2;
    const int EB4 = (nv4 + 256) / 256 + 1;   // covers vector part + tail
    const int NB = (N + 255) / 256;
    const int FB = 2048;   // 8 blocks/CU; window footprint set by PASSES=8

    if (use_bf) {
        int n8 = N * D / 8;
        k_cvt<<<(n8 + 255) / 256, 256, 0, stream>>>(x, xb, n8);
    }
    const unsigned int* xbp = use_bf ? (const unsigned int*)xb : nullptr;

    if (!fuse) {
        k_deg_s<<<EB4, 256, 0, stream>>>(src, ds_rep, E, N);
        k_norm_s<<<NB, 256, 0, stream>>>(ds_rep, nsrc, N);
    }

    if (use_rep) {
        if (fuse) {
            k_fill_t<8, 16, true><<<FB, 256, 0, stream>>>(src, dst, outrep,
                                                          cnt, csr, E, N);
            k_norm_s<<<NB, 256, 0, stream>>>(outrep, nsrc, N);
        } else {
            k_fill_t<8, 16, false><<<FB, 256, 0, stream>>>(src, dst, nullptr,
                                                           cnt, csr, E, N);
        }
        k_agg<8, 16><<<(N + 3) / 4, 256, 0, stream>>>(csr, cnt, nsrc, xbp, x,
                                                      agg, N);
    } else {
        k_fill_t<1, 64, false><<<FB, 256, 0, stream>>>(src, dst, nullptr,
                                                       cnt, csr, E, N);
        k_agg<1, 64><<<(N + 3) / 4, 256, 0, stream>>>(csr, cnt, nsrc, xbp, x,
                                                      agg, N);
    }
    k_gemm_norm<<<(N + 63) / 64, 256, 0, stream>>>(agg, x, W, bias, out, N);
}